// Round 18
// baseline (1953.051 us; speedup 1.0000x reference)
//
#include <hip/hip_runtime.h>
#include <stdint.h>

// Problem constants
#define Bb   128
#define Tt   256
#define Nn   4
#define Dd   64
#define Hh   256
#define G4H  1024          // 4*H
#define MR   64            // episode lanes (rows) per work item

// d_out layout: output (B,T,N,H) | h_n (B,N,L,H) | c_n (B,N,L,H)
#define OUT_HN 33554432    // 128*256*4*256
#define OUT_CN 33816576    // OUT_HN + 128*4*2*256

// workspace byte offsets
#define WS_CTRL 0          // 64 ints: [0]=stride mode, [1]=E, [2]=nchunks, [4..7]=work ctrs
#define WS_SORT 8192       // 32768 u32 packed episodes (sorted desc by len)
#define WS_BIAS 139264     // N*2*1024 f32 packed bias
#define WS_WPK  262144     // packed bf16 weights: 4 agents * 1664 tiles * 1KB
#define TILES_PER_AGENT 1664   // 64 ntiles * (10 kb L0 + 16 kb L1)

typedef __attribute__((ext_vector_type(4))) float f32x4;
typedef __attribute__((ext_vector_type(8))) short bf16x8;

__device__ __forceinline__ unsigned short f2bf(float f){
  union { float f; unsigned u; } v; v.f = f;
  unsigned r = v.u + 0x7FFFu + ((v.u >> 16) & 1u);  // RNE
  return (unsigned short)(r >> 16);
}
__device__ __forceinline__ float bf2f(short s){
  union { unsigned u; float f; } v; v.u = ((unsigned)(unsigned short)s) << 16;
  return v.f;
}
__device__ __forceinline__ float sigm(float x){
  return __builtin_amdgcn_rcpf(1.f + __expf(-x));
}
__device__ __forceinline__ float tanh_s(float x){
  return 1.f - 2.f * __builtin_amdgcn_rcpf(1.f + __expf(2.f * x));
}

// LDS-only barrier: drains DS ops but NOT vmcnt -> in-flight weight loads
// (plain global_load into VGPRs) survive across barriers.
__device__ __forceinline__ void lds_barrier(){
  asm volatile("s_waitcnt lgkmcnt(0)" ::: "memory");
  __builtin_amdgcn_s_barrier();
  __builtin_amdgcn_sched_barrier(0);
}

// ---- LDS swizzle helpers (XOR bit4 with row&7 -> conflict-free b128 column reads) ----
__device__ __forceinline__ void st_h(unsigned short* hl, int row, int col, unsigned short v){
  int off = (row * (Hh*2) + col * 2) ^ ((row & 7) << 4);
  *(unsigned short*)((char*)hl + off) = v;
}
__device__ __forceinline__ bf16x8 ld_hfrag(const unsigned short* hl, int m, int kb, int l){
  int row = m*16 + (l & 15);
  int off = (row * (Hh*2) + kb*64 + ((l >> 4) << 4)) ^ ((row & 7) << 4);
  return *(const bf16x8*)((const char*)hl + off);
}
__device__ __forceinline__ bf16x8 ld_xfrag(const unsigned short* xl, int m, int kb, int l){
  int row = m*16 + (l & 15);
  int off = (row * (Dd*2) + kb*64 + ((l >> 4) << 4)) ^ ((row & 7) << 4);
  return *(const bf16x8*)((const char*)xl + off);
}

__device__ __forceinline__ bool get_flag(const unsigned char* p, int t, int stride){
  if (stride == 1) return p[t] != 0;
  return ((const int*)p)[t] != 0;
}

// ============== prep kernels (2 dispatches before k_main) ==============

// Fused: detect stride + histogram + scan + scatter (one 128-thread block).
__global__ void k_prep(const unsigned char* ii, int* ctrl, unsigned int* sorted){
  __shared__ int s_cnt;
  __shared__ int hist_s[Tt + 1];
  __shared__ int offs_s[Tt + 1];
  int tid = threadIdx.x;          // 128 threads, one per b
  if (tid == 0) s_cnt = 0;
  for (int i = tid; i <= Tt; i += 128) hist_s[i] = 0;
  __syncthreads();
  atomicAdd(&s_cnt, (ii[2*tid] != 0) + (ii[2*tid+1] != 0));
  __syncthreads();
  int stride = (s_cnt > 80) ? 1 : 4;
  if (tid == 0) ctrl[0] = stride;
  const unsigned char* p = ii + (size_t)tid * Tt * stride;
  int start = 0;
  for (int t = 1; t < Tt; t++){
    if (get_flag(p, t, stride)){ atomicAdd(&hist_s[t - start], 1); start = t; }
  }
  atomicAdd(&hist_s[Tt - start], 1);
  __syncthreads();
  if (tid == 0){
    int run = 0;
    for (int len = Tt; len >= 1; len--){ offs_s[len] = run; run += hist_s[len]; }
    ctrl[1] = run;                     // E
    ctrl[2] = (run + MR - 1) / MR;     // nchunks
  }
  __syncthreads();
  start = 0;
  for (int t = 1; t < Tt; t++){
    if (get_flag(p, t, stride)){
      int len = t - start;
      int pos = atomicAdd(&offs_s[len], 1);
      sorted[pos] = 0x80000000u | ((unsigned)tid << 16) | ((unsigned)start << 8) | (unsigned)(len - 1);
      start = t;
    }
  }
  int len = Tt - start;
  int pos = atomicAdd(&offs_s[len], 1);
  sorted[pos] = 0x80000000u | ((unsigned)tid << 16) | ((unsigned)start << 8) | (unsigned)(len - 1);
}

__global__ void k_packw(const float* __restrict__ Wih0, const float* __restrict__ Whh0,
                        const float* __restrict__ Wih1, const float* __restrict__ Whh1,
                        const float* __restrict__ bih0, const float* __restrict__ bhh0,
                        const float* __restrict__ bih1, const float* __restrict__ bhh1,
                        unsigned short* __restrict__ wpk, float* __restrict__ bpk){
  int bid = blockIdx.x;            // 0..6655
  int l = threadIdx.x;             // 0..63
  int n = bid / TILES_PER_AGENT;
  int r = bid % TILES_PER_AGENT;
  int layer, ntile, kb;
  if (r < 640){ layer = 0; ntile = r / 10; kb = r % 10; }
  else        { layer = 1; r -= 640; ntile = r / 16; kb = r % 16; }
  int col_sub = l >> 2;
  int k8      = (l & 3) * 8;
  int col  = ntile*16 + col_sub;
  int grow = (col & 3)*Hh + (col >> 2);
  const float* src;
  if (layer == 0){
    if (kb < 2) src = Wih0 + ((size_t)(n*G4H + grow))*Dd + kb*32 + k8;
    else        src = Whh0 + ((size_t)(n*G4H + grow))*Hh + (kb-2)*32 + k8;
  } else {
    if (kb < 8) src = Wih1 + ((size_t)(n*G4H + grow))*Hh + kb*32 + k8;
    else        src = Whh1 + ((size_t)(n*G4H + grow))*Hh + (kb-8)*32 + k8;
  }
  int tl = (layer == 0) ? (ntile*10 + kb) : (640 + ntile*16 + kb);
  int lp = ((l & 3) << 4) | (l >> 2);
  unsigned short* dst = wpk + (((size_t)n*TILES_PER_AGENT + tl)*64 + lp)*8;
  #pragma unroll
  for (int j = 0; j < 8; j++) dst[j] = f2bf(src[j]);

  int id = bid*64 + l;
  if (id < Nn*2*G4H){
    int nb = id >> 11; int rb = id & 2047; int lyr = rb >> 10; int c = rb & 1023;
    int gr = (c & 3)*Hh + (c >> 2);
    float v = (lyr == 0) ? (bih0[nb*G4H + gr] + bhh0[nb*G4H + gr])
                         : (bih1[nb*G4H + gr] + bhh1[nb*G4H + gr]);
    bpk[id] = v;
  }
}

// ============== main kernel ==============
// R18 = R16 structure at the LEGAL budget. Register law (R15/R16/R17):
// per-wave budget is VGPR+AGPR COMBINED; 2 waves/SIMD -> 256 total,
// 1 wave/SIMD -> 512 total. MR=64 @ 256 threads needs acc[16][4] = 256 AGPR;
// at (256,1) that leaves 256 VGPRs. c-state is PACKED AS BF16 PAIRS
// (128 -> 64 VGPRs; recomputed in f32 each step; ~0.4%/step rounding on a
// 6x absmax margin) -> VGPR ~190 + AGPR 256 ~= 446 <= 512. vs R14: 2x
// arithmetic per load (64 MFMA/kb vs 16 in-flight loads) -> L2 latency fully
// covered -> per-step toward the 11.5us L2-port floor (R14: 28us).
__launch_bounds__(256, 1)
__global__ void k_main(const float* __restrict__ x_in,
                       const unsigned short* __restrict__ wpk,
                       const float* __restrict__ bpk,
                       const unsigned int* __restrict__ sorted,
                       int* __restrict__ ctrl,
                       float* __restrict__ out)
{
  __shared__ unsigned short h0l[MR*Hh];     // 32KB, swizzled bf16
  __shared__ unsigned short h1l[MR*Hh];     // 32KB
  __shared__ unsigned short xl [MR*Dd];     // 8KB
  __shared__ unsigned short biasl[2*G4H];   // 4KB bf16 packed bias
  __shared__ unsigned int epl[MR];
  __shared__ int item_s;

  const int tid = threadIdx.x;
  const int w   = tid >> 6;                 // wave 0..3
  const int l   = tid & 63;
  const int n   = (blockIdx.x >> 1) & 3;    // static agent; 64 blocks/agent
  const int E       = ctrl[1];
  const int nchunks = ctrl[2];

  const unsigned short* wbase = wpk + (size_t)n * TILES_PER_AGENT * 64 * 8;

  for (int i = tid; i < 2*G4H; i += 256) biasl[i] = f2bf(bpk[n*2*G4H + i]);

  const int nrow = l & 15;
  const int nul  = l >> 4;

  // Weight unit: 8 tiles (i = h*8 + j, j<8) of (layer,kb) for this wave,
  // loaded straight into VGPRs. Tile id: L0 = t*10+kb, L1 = 640+t*16+kb.
  #define LOADW(dstv, layer, kb, h)                                          \
    { int base_ = ((layer)==0) ? ((w*16 + (h)*8)*10 + (kb))                  \
                               : (640 + (w*16 + (h)*8)*16 + (kb));           \
      int str_  = ((layer)==0) ? 10 : 16;                                    \
      _Pragma("unroll")                                                      \
      for (int j = 0; j < 8; j++)                                            \
        dstv[j] = *(const bf16x8*)(wbase + ((size_t)(base_ + j*str_)*64 + l)*8); \
      __builtin_amdgcn_sched_barrier(0); }

  #define MFMA8(wv, h)                                                       \
    { _Pragma("unroll")                                                      \
      for (int j = 0; j < 8; j++){                                           \
        int i_ = (h)*8 + j;                                                  \
        acc[i_][0] = __builtin_amdgcn_mfma_f32_16x16x32_bf16(wv[j], a0, acc[i_][0], 0, 0, 0); \
        acc[i_][1] = __builtin_amdgcn_mfma_f32_16x16x32_bf16(wv[j], a1, acc[i_][1], 0, 0, 0); \
        acc[i_][2] = __builtin_amdgcn_mfma_f32_16x16x32_bf16(wv[j], a2, acc[i_][2], 0, 0, 0); \
        acc[i_][3] = __builtin_amdgcn_mfma_f32_16x16x32_bf16(wv[j], a3, acc[i_][3], 0, 0, 0); \
      } }

  // Nonlinearity for tile i, m-pair mp (m = 2mp, 2mp+1) with bf16-packed c.
  // cp: u32 = bf16(c[2mp]) | bf16(c[2mp+1])<<16. Writes h to hl, finals to out.
  #define NONLIN_PAIR(cp, g0, g1, i, mp, hl, layerofs)                       \
    { float cl = bf2f((short)((cp) & 0xffff));                               \
      float ch = bf2f((short)((cp) >> 16));                                  \
      float cn0 = sigm((g0)[1])*cl + sigm((g0)[0])*tanh_s((g0)[2]);          \
      float hn0 = sigm((g0)[3])*tanh_s(cn0);                                 \
      float cn1 = sigm((g1)[1])*ch + sigm((g1)[0])*tanh_s((g1)[2]);          \
      float hn1 = sigm((g1)[3])*tanh_s(cn1);                                 \
      (cp) = (unsigned)f2bf(cn0) | ((unsigned)f2bf(cn1) << 16);              \
      int unit = (w*16 + (i))*4 + nul;                                       \
      int row0 = (2*(mp))*16 + nrow;                                         \
      int row1 = (2*(mp)+1)*16 + nrow;                                       \
      st_h(hl, row0, unit, f2bf(hn0));                                       \
      st_h(hl, row1, unit, f2bf(hn1));                                       \
      unsigned int pk0 = epl[row0];                                          \
      if (pk0 >> 31){                                                        \
        int len = (int)(pk0 & 255) + 1; int start = (pk0 >> 8) & 255;        \
        if (s == len - 1 && start + len == Tt){                              \
          int b = (pk0 >> 16) & 127;                                         \
          size_t base = ((size_t)(b*Nn + n)*2 + (layerofs))*Hh + unit;       \
          out[OUT_HN + base] = hn0; out[OUT_CN + base] = cn0;                \
        } }                                                                  \
      unsigned int pk1 = epl[row1];                                          \
      if (pk1 >> 31){                                                        \
        int len = (int)(pk1 & 255) + 1; int start = (pk1 >> 8) & 255;        \
        if (s == len - 1 && start + len == Tt){                              \
          int b = (pk1 >> 16) & 127;                                         \
          size_t base = ((size_t)(b*Nn + n)*2 + (layerofs))*Hh + unit;       \
          out[OUT_HN + base] = hn1; out[OUT_CN + base] = cn1;                \
        } } }

  while (true){
    __syncthreads();                         // full drain (chunk boundary)
    if (tid == 0) item_s = atomicAdd(&ctrl[4 + n], 1);
    __syncthreads();
    int chunk = item_s;
    if (chunk >= nchunks) break;

    if (tid < MR){
      int idx = chunk*MR + tid;
      epl[tid] = (idx < E) ? sorted[idx] : 0u;
    }
    for (int i = tid; i < MR*Hh/4; i += 256){
      ((ushort4*)h0l)[i] = make_ushort4(0,0,0,0);
      ((ushort4*)h1l)[i] = make_ushort4(0,0,0,0);
    }
    __syncthreads();

    unsigned int ep0 = epl[0];
    int maxlen = (ep0 >> 31) ? (int)(ep0 & 255) + 1 : 0;

    // bf16-packed c state: [tile][m-pair], 2 layers -> 64 VGPRs
    unsigned c0p[16][2], c1p[16][2];
    #pragma unroll
    for (int i = 0; i < 16; i++)
      #pragma unroll
      for (int mp = 0; mp < 2; mp++){ c0p[i][mp] = 0u; c1p[i][mp] = 0u; }

    bf16x8 wA[8], wB[8];
    LOADW(wA, 0, 0, 0);          // prime: L0 kb=0, halves 0/1
    LOADW(wB, 0, 0, 1);

    #pragma unroll 1
    for (int s = 0; s < maxlen; s++){
      // ---- stage x_t (fp32 -> bf16, swizzled; zeros for finished lanes) ----
      #pragma unroll
      for (int r2 = 0; r2 < 4; r2++){
        int row = r2*16 + (tid >> 4);
        int d4  = (tid & 15) * 4;
        unsigned int pk = epl[row];
        int len = (pk >> 31) ? (int)(pk & 255) + 1 : 0;
        ushort4 u = make_ushort4(0,0,0,0);
        if (s < len){
          int b = (pk >> 16) & 127;
          int t = (int)((pk >> 8) & 255) + s;
          const float* xp = x_in + (((size_t)b*Tt + t)*Nn + n)*Dd + d4;
          f32x4 v = *(const f32x4*)xp;
          u.x = f2bf(v[0]); u.y = f2bf(v[1]); u.z = f2bf(v[2]); u.w = f2bf(v[3]);
        }
        int off = (row*(Dd*2) + d4*2) ^ ((row & 7) << 4);
        *(ushort4*)((char*)xl + off) = u;
      }
      lds_barrier();                                   // bar 1: xl ready

      // ================= LAYER 0 GEMM =================
      {
        f32x4 acc[16][4];
        #pragma unroll
        for (int i = 0; i < 16; i++){
          ushort4 bu = *(const ushort4*)&biasl[(w*16 + i)*16 + nul*4];
          f32x4 bv = { bf2f((short)bu.x), bf2f((short)bu.y),
                       bf2f((short)bu.z), bf2f((short)bu.w) };
          #pragma unroll
          for (int m = 0; m < 4; m++) acc[i][m] = bv;
        }
        #pragma unroll 1
        for (int kb = 0; kb < 10; kb++){
          bf16x8 a0, a1, a2, a3;
          if (kb < 2){
            a0 = ld_xfrag(xl, 0, kb, l); a1 = ld_xfrag(xl, 1, kb, l);
            a2 = ld_xfrag(xl, 2, kb, l); a3 = ld_xfrag(xl, 3, kb, l);
          } else {
            a0 = ld_hfrag(h0l, 0, kb-2, l); a1 = ld_hfrag(h0l, 1, kb-2, l);
            a2 = ld_hfrag(h0l, 2, kb-2, l); a3 = ld_hfrag(h0l, 3, kb-2, l);
          }
          MFMA8(wA, 0);
          if (kb < 9) { LOADW(wA, 0, kb+1, 0); } else { LOADW(wA, 1, 0, 0); }
          MFMA8(wB, 1);
          if (kb < 9) { LOADW(wB, 0, kb+1, 1); } else { LOADW(wB, 1, 0, 1); }
        }
        lds_barrier();   // bar 2: all waves done reading h0l(old)/xl

        // L0 nonlin (packed c); L1 unit-0 loads fly underneath.
        #pragma unroll
        for (int i = 0; i < 16; i++){
          #pragma unroll
          for (int mp = 0; mp < 2; mp++){
            NONLIN_PAIR(c0p[i][mp], acc[i][2*mp], acc[i][2*mp+1], i, mp, h0l, 0);
          }
        }
      }
      lds_barrier();   // bar 3: h0_new visible

      // ================= LAYER 1 GEMM =================
      {
        f32x4 acc[16][4];
        #pragma unroll
        for (int i = 0; i < 16; i++){
          ushort4 bu = *(const ushort4*)&biasl[G4H + (w*16 + i)*16 + nul*4];
          f32x4 bv = { bf2f((short)bu.x), bf2f((short)bu.y),
                       bf2f((short)bu.z), bf2f((short)bu.w) };
          #pragma unroll
          for (int m = 0; m < 4; m++) acc[i][m] = bv;
        }
        #pragma unroll 1
        for (int kb = 0; kb < 16; kb++){
          bf16x8 a0, a1, a2, a3;
          if (kb < 8){
            a0 = ld_hfrag(h0l, 0, kb, l); a1 = ld_hfrag(h0l, 1, kb, l);
            a2 = ld_hfrag(h0l, 2, kb, l); a3 = ld_hfrag(h0l, 3, kb, l);
          } else {
            a0 = ld_hfrag(h1l, 0, kb-8, l); a1 = ld_hfrag(h1l, 1, kb-8, l);
            a2 = ld_hfrag(h1l, 2, kb-8, l); a3 = ld_hfrag(h1l, 3, kb-8, l);
          }
          MFMA8(wA, 0);
          if (kb < 15) { LOADW(wA, 1, kb+1, 0); } else { LOADW(wA, 0, 0, 0); }
          MFMA8(wB, 1);
          if (kb < 15) { LOADW(wB, 1, kb+1, 1); } else { LOADW(wB, 0, 0, 1); }
        }
        lds_barrier();   // bar 4: all waves done reading h0_new/h1l(old)

        // L1 nonlin (packed c). Next step's L0 unit-0 loads in flight.
        #pragma unroll
        for (int i = 0; i < 16; i++){
          #pragma unroll
          for (int mp = 0; mp < 2; mp++){
            NONLIN_PAIR(c1p[i][mp], acc[i][2*mp], acc[i][2*mp+1], i, mp, h1l, 1);
          }
        }
      }
      lds_barrier();   // bar 5: h1_new visible for output read

      // ---- output write: output[b, t, n, :] = h1_new (256B segments) ----
      #pragma unroll
      for (int r2 = 0; r2 < 4; r2++){
        int row = r2*16 + (tid >> 4);
        unsigned int pk = epl[row];
        int len = (pk >> 31) ? (int)(pk & 255) + 1 : 0;
        if (s < len){
          int b = (pk >> 16) & 127;
          int t = (int)((pk >> 8) & 255) + s;
          int l16 = tid & 15;
          int swz = (row & 7) << 4;
          float* op = out + (((size_t)b*Tt + t)*Nn + n)*Hh;
          #pragma unroll
          for (int k = 0; k < 4; k++){
            int off = (row*(Hh*2) + k*128 + l16*8) ^ swz;
            ushort4 u = *(const ushort4*)((const char*)h1l + off);
            f32x4 v = { bf2f((short)u.x), bf2f((short)u.y), bf2f((short)u.z), bf2f((short)u.w) };
            *(f32x4*)(op + k*64 + l16*4) = v;
          }
        }
      }
      // no trailing barrier: next h1l writers are >=3 barriers away
    } // s loop
  } // work loop
  #undef LOADW
  #undef MFMA8
  #undef NONLIN_PAIR
}

// ============== launch ==============
extern "C" void kernel_launch(void* const* d_in, const int* in_sizes, int n_in,
                              void* d_out, int out_size, void* d_ws, size_t ws_size,
                              hipStream_t stream)
{
  const float* x    = (const float*)d_in[0];
  const unsigned char* ii = (const unsigned char*)d_in[1];
  const float* Wih0 = (const float*)d_in[2];
  const float* Whh0 = (const float*)d_in[3];
  const float* bih0 = (const float*)d_in[4];
  const float* bhh0 = (const float*)d_in[5];
  const float* Wih1 = (const float*)d_in[6];
  const float* Whh1 = (const float*)d_in[7];
  const float* bih1 = (const float*)d_in[8];
  const float* bhh1 = (const float*)d_in[9];
  float* out = (float*)d_out;
  char* ws = (char*)d_ws;

  int* ctrl = (int*)(ws + WS_CTRL);
  unsigned int* sorted = (unsigned int*)(ws + WS_SORT);
  float* bpk = (float*)(ws + WS_BIAS);
  unsigned short* wpkp = (unsigned short*)(ws + WS_WPK);

  hipMemsetAsync(d_ws, 0, 1024, stream);
  k_prep  <<<1, 128, 0, stream>>>(ii, ctrl, sorted);
  k_packw <<<Nn*TILES_PER_AGENT, 64, 0, stream>>>(Wih0, Whh0, Wih1, Whh1,
                                                  bih0, bhh0, bih1, bhh1, wpkp, bpk);
  k_main  <<<256, 256, 0, stream>>>(x, wpkp, bpk, sorted, ctrl, out);
}

// Round 19
// 750.723 us; speedup vs baseline: 2.6016x; 2.6016x over previous
//
#include <hip/hip_runtime.h>
#include <stdint.h>

// Problem constants
#define Bb   128
#define Tt   256
#define Nn   4
#define Dd   64
#define Hh   256
#define G4H  1024          // 4*H
#define MR   32            // episode lanes (rows) per work item

// d_out layout: output (B,T,N,H) | h_n (B,N,L,H) | c_n (B,N,L,H)
#define OUT_HN 33554432    // 128*256*4*256
#define OUT_CN 33816576    // OUT_HN + 128*4*2*256

// workspace byte offsets
#define WS_CTRL 0          // 64 ints: [0]=stride mode, [1]=E, [2]=nchunks, [4..7]=work ctrs
#define WS_SORT 8192       // 32768 u32 packed episodes (sorted desc by len)
#define WS_BIAS 139264     // N*2*1024 f32 packed bias
#define WS_WPK  262144     // packed bf16 weights: 4 agents * 1664 tiles * 1KB
#define TILES_PER_AGENT 1664   // 64 ntiles * (10 kb L0 + 16 kb L1)

typedef __attribute__((ext_vector_type(4))) float f32x4;
typedef __attribute__((ext_vector_type(8))) short bf16x8;

__device__ __forceinline__ unsigned short f2bf(float f){
  union { float f; unsigned u; } v; v.f = f;
  unsigned r = v.u + 0x7FFFu + ((v.u >> 16) & 1u);  // RNE
  return (unsigned short)(r >> 16);
}
__device__ __forceinline__ float bf2f(short s){
  union { unsigned u; float f; } v; v.u = ((unsigned)(unsigned short)s) << 16;
  return v.f;
}
__device__ __forceinline__ float sigm(float x){
  return __builtin_amdgcn_rcpf(1.f + __expf(-x));
}
__device__ __forceinline__ float tanh_s(float x){
  return 1.f - 2.f * __builtin_amdgcn_rcpf(1.f + __expf(2.f * x));
}

// LDS-only barrier: drains DS ops but NOT vmcnt -> in-flight weight loads
// (plain global_load into VGPRs) survive across barriers.
__device__ __forceinline__ void lds_barrier(){
  asm volatile("s_waitcnt lgkmcnt(0)" ::: "memory");
  __builtin_amdgcn_s_barrier();
  __builtin_amdgcn_sched_barrier(0);
}

// ---- LDS swizzle helpers (XOR bit4 with row&7 -> conflict-free b128 column reads) ----
__device__ __forceinline__ void st_h(unsigned short* hl, int row, int col, unsigned short v){
  int off = (row * (Hh*2) + col * 2) ^ ((row & 7) << 4);
  *(unsigned short*)((char*)hl + off) = v;
}
__device__ __forceinline__ bf16x8 ld_hfrag(const unsigned short* hl, int m, int kb, int l){
  int row = m*16 + (l & 15);
  int off = (row * (Hh*2) + kb*64 + ((l >> 4) << 4)) ^ ((row & 7) << 4);
  return *(const bf16x8*)((const char*)hl + off);
}
__device__ __forceinline__ bf16x8 ld_xfrag(const unsigned short* xl, int m, int kb, int l){
  int row = m*16 + (l & 15);
  int off = (row * (Dd*2) + kb*64 + ((l >> 4) << 4)) ^ ((row & 7) << 4);
  return *(const bf16x8*)((const char*)xl + off);
}

__device__ __forceinline__ bool get_flag(const unsigned char* p, int t, int stride){
  if (stride == 1) return p[t] != 0;
  return ((const int*)p)[t] != 0;
}

// ============== prep kernels (2 dispatches before k_main) ==============

// Fused: detect stride + histogram + scan + scatter (one 128-thread block).
__global__ void k_prep(const unsigned char* ii, int* ctrl, unsigned int* sorted){
  __shared__ int s_cnt;
  __shared__ int hist_s[Tt + 1];
  __shared__ int offs_s[Tt + 1];
  int tid = threadIdx.x;          // 128 threads, one per b
  if (tid == 0) s_cnt = 0;
  for (int i = tid; i <= Tt; i += 128) hist_s[i] = 0;
  __syncthreads();
  atomicAdd(&s_cnt, (ii[2*tid] != 0) + (ii[2*tid+1] != 0));
  __syncthreads();
  int stride = (s_cnt > 80) ? 1 : 4;
  if (tid == 0) ctrl[0] = stride;
  const unsigned char* p = ii + (size_t)tid * Tt * stride;
  int start = 0;
  for (int t = 1; t < Tt; t++){
    if (get_flag(p, t, stride)){ atomicAdd(&hist_s[t - start], 1); start = t; }
  }
  atomicAdd(&hist_s[Tt - start], 1);
  __syncthreads();
  if (tid == 0){
    int run = 0;
    for (int len = Tt; len >= 1; len--){ offs_s[len] = run; run += hist_s[len]; }
    ctrl[1] = run;                     // E
    ctrl[2] = (run + MR - 1) / MR;     // nchunks
  }
  __syncthreads();
  start = 0;
  for (int t = 1; t < Tt; t++){
    if (get_flag(p, t, stride)){
      int len = t - start;
      int pos = atomicAdd(&offs_s[len], 1);
      sorted[pos] = 0x80000000u | ((unsigned)tid << 16) | ((unsigned)start << 8) | (unsigned)(len - 1);
      start = t;
    }
  }
  int len = Tt - start;
  int pos = atomicAdd(&offs_s[len], 1);
  sorted[pos] = 0x80000000u | ((unsigned)tid << 16) | ((unsigned)start << 8) | (unsigned)(len - 1);
}

__global__ void k_packw(const float* __restrict__ Wih0, const float* __restrict__ Whh0,
                        const float* __restrict__ Wih1, const float* __restrict__ Whh1,
                        const float* __restrict__ bih0, const float* __restrict__ bhh0,
                        const float* __restrict__ bih1, const float* __restrict__ bhh1,
                        unsigned short* __restrict__ wpk, float* __restrict__ bpk){
  int bid = blockIdx.x;            // 0..6655
  int l = threadIdx.x;             // 0..63
  int n = bid / TILES_PER_AGENT;
  int r = bid % TILES_PER_AGENT;
  int layer, ntile, kb;
  if (r < 640){ layer = 0; ntile = r / 10; kb = r % 10; }
  else        { layer = 1; r -= 640; ntile = r / 16; kb = r % 16; }
  int col_sub = l >> 2;
  int k8      = (l & 3) * 8;
  int col  = ntile*16 + col_sub;
  int grow = (col & 3)*Hh + (col >> 2);
  const float* src;
  if (layer == 0){
    if (kb < 2) src = Wih0 + ((size_t)(n*G4H + grow))*Dd + kb*32 + k8;
    else        src = Whh0 + ((size_t)(n*G4H + grow))*Hh + (kb-2)*32 + k8;
  } else {
    if (kb < 8) src = Wih1 + ((size_t)(n*G4H + grow))*Hh + kb*32 + k8;
    else        src = Whh1 + ((size_t)(n*G4H + grow))*Hh + (kb-8)*32 + k8;
  }
  int tl = (layer == 0) ? (ntile*10 + kb) : (640 + ntile*16 + kb);
  int lp = ((l & 3) << 4) | (l >> 2);
  unsigned short* dst = wpk + (((size_t)n*TILES_PER_AGENT + tl)*64 + lp)*8;
  #pragma unroll
  for (int j = 0; j < 8; j++) dst[j] = f2bf(src[j]);

  int id = bid*64 + l;
  if (id < Nn*2*G4H){
    int nb = id >> 11; int rb = id & 2047; int lyr = rb >> 10; int c = rb & 1023;
    int gr = (c & 3)*Hh + (c >> 2);
    float v = (lyr == 0) ? (bih0[nb*G4H + gr] + bhh0[nb*G4H + gr])
                         : (bih1[nb*G4H + gr] + bhh1[nb*G4H + gr]);
    bpk[id] = v;
  }
}

// ============== main kernel ==============
// FINAL (= R14, verified 704us k_main / 745us total, clean counters).
// 256 blocks x 256 threads (4 waves), 1 block/CU forced via LDS pad;
// 1 wave/SIMD. Register law established over R3-R18: only 128 AGPR-able
// accumulator f32 + ~250 VALU-visible VGPRs fit without spill (the 256
// addressable-VGPR encoding limit binds regardless of the 512-reg unified
// file); every attempt to exceed this working set (deeper rings, MR=64
// variants, 2-blocks/CU) spilled to scratch and regressed 2-6x.
// Weights stream L2->VGPR via depth-2 ping-pong (wA/wB, 8 tiles each);
// the issue chain crosses layers and steps; lds_barrier never drains vmcnt.
// Agent = (blockIdx>>1)&3 (deterministic); episodes sorted desc and packed
// 32/chunk; h-state in swizzled LDS, c-state in registers.
__launch_bounds__(256, 1)
__global__ void k_main(const float* __restrict__ x_in,
                       const unsigned short* __restrict__ wpk,
                       const float* __restrict__ bpk,
                       const unsigned int* __restrict__ sorted,
                       int* __restrict__ ctrl,
                       float* __restrict__ out)
{
  __shared__ unsigned short h0l[MR*Hh];     // 16KB, swizzled bf16
  __shared__ unsigned short h1l[MR*Hh];     // 16KB
  __shared__ unsigned short xl [MR*Dd];     // 4KB
  __shared__ unsigned short biasl[2*G4H];   // 4KB bf16 packed bias
  __shared__ unsigned int epl[MR];
  __shared__ int item_s;
  __shared__ char lds_pad[45056];           // pad -> ~85KB total -> 1 block/CU

  const int tid = threadIdx.x;
  const int w   = tid >> 6;                 // wave 0..3
  const int l   = tid & 63;
  const int n   = (blockIdx.x >> 1) & 3;    // static agent; 64 blocks/agent
  const int E       = ctrl[1];
  const int nchunks = ctrl[2];

  // keep the pad allocated (runtime-opaque condition, never true)
  if (E == -2147483647) lds_pad[tid] = 1;

  const unsigned short* wbase = wpk + (size_t)n * TILES_PER_AGENT * 64 * 8;

  for (int i = tid; i < 2*G4H; i += 256) biasl[i] = f2bf(bpk[n*2*G4H + i]);

  const int nrow = l & 15;
  const int nul  = l >> 4;

  // Weight unit: 8 tiles (i = h*8 + j, j<8) of (layer,kb) for this wave,
  // loaded straight into VGPRs. Tile id: L0 = t*10+kb, L1 = 640+t*16+kb.
  #define LOADW(dstv, layer, kb, h)                                          \
    { int base_ = ((layer)==0) ? ((w*16 + (h)*8)*10 + (kb))                  \
                               : (640 + (w*16 + (h)*8)*16 + (kb));           \
      int str_  = ((layer)==0) ? 10 : 16;                                    \
      _Pragma("unroll")                                                      \
      for (int j = 0; j < 8; j++)                                            \
        dstv[j] = *(const bf16x8*)(wbase + ((size_t)(base_ + j*str_)*64 + l)*8); \
      __builtin_amdgcn_sched_barrier(0); }

  #define MFMA8(wv, h)                                                       \
    { _Pragma("unroll")                                                      \
      for (int j = 0; j < 8; j++){                                           \
        int i_ = (h)*8 + j;                                                  \
        acc[i_][0] = __builtin_amdgcn_mfma_f32_16x16x32_bf16(wv[j], a0, acc[i_][0], 0, 0, 0); \
        acc[i_][1] = __builtin_amdgcn_mfma_f32_16x16x32_bf16(wv[j], a1, acc[i_][1], 0, 0, 0); \
      } }

  while (true){
    __syncthreads();                         // full drain (chunk boundary)
    if (tid == 0) item_s = atomicAdd(&ctrl[4 + n], 1);
    __syncthreads();
    int chunk = item_s;
    if (chunk >= nchunks) break;

    if (tid < MR){
      int idx = chunk*MR + tid;
      epl[tid] = (idx < E) ? sorted[idx] : 0u;
    }
    for (int i = tid; i < MR*Hh/4; i += 256){
      ((ushort4*)h0l)[i] = make_ushort4(0,0,0,0);
      ((ushort4*)h1l)[i] = make_ushort4(0,0,0,0);
    }
    __syncthreads();

    unsigned int ep0 = epl[0];
    int maxlen = (ep0 >> 31) ? (int)(ep0 & 255) + 1 : 0;

    float c0r[16][2], c1r[16][2];
    #pragma unroll
    for (int i = 0; i < 16; i++)
      #pragma unroll
      for (int m = 0; m < 2; m++){ c0r[i][m]=0.f; c1r[i][m]=0.f; }

    bf16x8 wA[8], wB[8];
    LOADW(wA, 0, 0, 0);          // prime: L0 kb=0, halves 0/1
    LOADW(wB, 0, 0, 1);

    #pragma unroll 1
    for (int s = 0; s < maxlen; s++){
      // ---- stage x_t (fp32 -> bf16, swizzled; zeros for finished lanes) ----
      #pragma unroll
      for (int r2 = 0; r2 < 2; r2++){
        int row = r2*16 + (tid >> 4);
        int d4  = (tid & 15) * 4;
        unsigned int pk = epl[row];
        int len = (pk >> 31) ? (int)(pk & 255) + 1 : 0;
        ushort4 u = make_ushort4(0,0,0,0);
        if (s < len){
          int b = (pk >> 16) & 127;
          int t = (int)((pk >> 8) & 255) + s;
          const float* xp = x_in + (((size_t)b*Tt + t)*Nn + n)*Dd + d4;
          f32x4 v = *(const f32x4*)xp;
          u.x = f2bf(v[0]); u.y = f2bf(v[1]); u.z = f2bf(v[2]); u.w = f2bf(v[3]);
        }
        int off = (row*(Dd*2) + d4*2) ^ ((row & 7) << 4);
        *(ushort4*)((char*)xl + off) = u;
      }
      lds_barrier();                                   // bar 1: xl ready

      // ================= LAYER 0 GEMM =================
      {
        f32x4 acc[16][2];
        #pragma unroll
        for (int i = 0; i < 16; i++){
          ushort4 bu = *(const ushort4*)&biasl[(w*16 + i)*16 + nul*4];
          f32x4 bv = { bf2f((short)bu.x), bf2f((short)bu.y),
                       bf2f((short)bu.z), bf2f((short)bu.w) };
          acc[i][0] = bv; acc[i][1] = bv;
        }
        #pragma unroll 1
        for (int kb = 0; kb < 10; kb++){
          bf16x8 a0, a1;
          if (kb < 2){ a0 = ld_xfrag(xl, 0, kb, l);    a1 = ld_xfrag(xl, 1, kb, l); }
          else       { a0 = ld_hfrag(h0l, 0, kb-2, l); a1 = ld_hfrag(h0l, 1, kb-2, l); }
          MFMA8(wA, 0);
          if (kb < 9) { LOADW(wA, 0, kb+1, 0); } else { LOADW(wA, 1, 0, 0); }
          MFMA8(wB, 1);
          if (kb < 9) { LOADW(wB, 0, kb+1, 1); } else { LOADW(wB, 1, 0, 1); }
        }
        lds_barrier();   // bar 2: all waves done reading h0l(old)/xl

        // L0 nonlin: gates in acc regs; writes h0l (new). L1 unit-0 loads
        // fly underneath this VALU section.
        #pragma unroll
        for (int i = 0; i < 16; i++){
          #pragma unroll
          for (int m = 0; m < 2; m++){
            f32x4 g = acc[i][m];
            float cn = sigm(g[1])*c0r[i][m] + sigm(g[0])*tanh_s(g[2]);
            float hn = sigm(g[3])*tanh_s(cn);
            c0r[i][m] = cn;
            int row  = m*16 + nrow;
            int unit = (w*16 + i)*4 + nul;
            st_h(h0l, row, unit, f2bf(hn));
            unsigned int pk = epl[row];
            if (pk >> 31){
              int len = (int)(pk & 255) + 1;
              int start = (pk >> 8) & 255;
              if (s == len - 1 && start + len == Tt){
                int b = (pk >> 16) & 127;
                size_t base = ((size_t)(b*Nn + n)*2 + 0)*Hh + unit;
                out[OUT_HN + base] = hn;
                out[OUT_CN + base] = cn;
              }
            }
          }
        }
      }
      lds_barrier();   // bar 3: h0_new visible

      // ================= LAYER 1 GEMM =================
      {
        f32x4 acc[16][2];
        #pragma unroll
        for (int i = 0; i < 16; i++){
          ushort4 bu = *(const ushort4*)&biasl[G4H + (w*16 + i)*16 + nul*4];
          f32x4 bv = { bf2f((short)bu.x), bf2f((short)bu.y),
                       bf2f((short)bu.z), bf2f((short)bu.w) };
          acc[i][0] = bv; acc[i][1] = bv;
        }
        #pragma unroll 1
        for (int kb = 0; kb < 16; kb++){
          bf16x8 a0, a1;
          if (kb < 8){ a0 = ld_hfrag(h0l, 0, kb, l);   a1 = ld_hfrag(h0l, 1, kb, l); }
          else       { a0 = ld_hfrag(h1l, 0, kb-8, l); a1 = ld_hfrag(h1l, 1, kb-8, l); }
          MFMA8(wA, 0);
          if (kb < 15) { LOADW(wA, 1, kb+1, 0); } else { LOADW(wA, 0, 0, 0); }
          MFMA8(wB, 1);
          if (kb < 15) { LOADW(wB, 1, kb+1, 1); } else { LOADW(wB, 0, 0, 1); }
        }
        lds_barrier();   // bar 4: all waves done reading h0_new/h1l(old)

        // L1 nonlin: writes h1l (new). Next step's L0 unit-0 loads in flight.
        #pragma unroll
        for (int i = 0; i < 16; i++){
          #pragma unroll
          for (int m = 0; m < 2; m++){
            f32x4 g = acc[i][m];
            float cn = sigm(g[1])*c1r[i][m] + sigm(g[0])*tanh_s(g[2]);
            float hn = sigm(g[3])*tanh_s(cn);
            c1r[i][m] = cn;
            int row  = m*16 + nrow;
            int unit = (w*16 + i)*4 + nul;
            st_h(h1l, row, unit, f2bf(hn));
            unsigned int pk = epl[row];
            if (pk >> 31){
              int len = (int)(pk & 255) + 1;
              int start = (pk >> 8) & 255;
              if (s == len - 1 && start + len == Tt){
                int b = (pk >> 16) & 127;
                size_t base = ((size_t)(b*Nn + n)*2 + 1)*Hh + unit;
                out[OUT_HN + base] = hn;
                out[OUT_CN + base] = cn;
              }
            }
          }
        }
      }
      lds_barrier();   // bar 5: h1_new visible for output read

      // ---- output write: output[b, t, n, :] = h1_new (256B segments) ----
      #pragma unroll
      for (int r2 = 0; r2 < 2; r2++){
        int row = r2*16 + (tid >> 4);
        unsigned int pk = epl[row];
        int len = (pk >> 31) ? (int)(pk & 255) + 1 : 0;
        if (s < len){
          int b = (pk >> 16) & 127;
          int t = (int)((pk >> 8) & 255) + s;
          int l16 = tid & 15;
          int swz = (row & 7) << 4;
          float* op = out + (((size_t)b*Tt + t)*Nn + n)*Hh;
          #pragma unroll
          for (int k = 0; k < 4; k++){
            int off = (row*(Hh*2) + k*128 + l16*8) ^ swz;
            ushort4 u = *(const ushort4*)((const char*)h1l + off);
            f32x4 v = { bf2f((short)u.x), bf2f((short)u.y), bf2f((short)u.z), bf2f((short)u.w) };
            *(f32x4*)(op + k*64 + l16*4) = v;
          }
        }
      }
      // no trailing barrier: next h1l writers are >=3 barriers away
    } // s loop
  } // work loop
  #undef LOADW
  #undef MFMA8
}

// ============== launch ==============
extern "C" void kernel_launch(void* const* d_in, const int* in_sizes, int n_in,
                              void* d_out, int out_size, void* d_ws, size_t ws_size,
                              hipStream_t stream)
{
  const float* x    = (const float*)d_in[0];
  const unsigned char* ii = (const unsigned char*)d_in[1];
  const float* Wih0 = (const float*)d_in[2];
  const float* Whh0 = (const float*)d_in[3];
  const float* bih0 = (const float*)d_in[4];
  const float* bhh0 = (const float*)d_in[5];
  const float* Wih1 = (const float*)d_in[6];
  const float* Whh1 = (const float*)d_in[7];
  const float* bih1 = (const float*)d_in[8];
  const float* bhh1 = (const float*)d_in[9];
  float* out = (float*)d_out;
  char* ws = (char*)d_ws;

  int* ctrl = (int*)(ws + WS_CTRL);
  unsigned int* sorted = (unsigned int*)(ws + WS_SORT);
  float* bpk = (float*)(ws + WS_BIAS);
  unsigned short* wpkp = (unsigned short*)(ws + WS_WPK);

  hipMemsetAsync(d_ws, 0, 1024, stream);
  k_prep  <<<1, 128, 0, stream>>>(ii, ctrl, sorted);
  k_packw <<<Nn*TILES_PER_AGENT, 64, 0, stream>>>(Wih0, Whh0, Wih1, Whh1,
                                                  bih0, bhh0, bih1, bhh1, wpkp, bpk);
  k_main  <<<256, 256, 0, stream>>>(x, wpkp, bpk, sorted, ctrl, out);
}